// Round 5
// baseline (102.910 us; speedup 1.0000x reference)
//
#include <hip/hip_runtime.h>

// Problem: B=4096, D=2, H=2048.
// e = sum_d enc[b,d,h]; d = sum_d dec[b,d,h]; S = e @ d^T (4096x4096)
// M = S on diag, -S off diag; LL = log_sigmoid(M)
// logLoss = -(sum(LL) + 39*sum(diag LL))/B ; diagonalLoss = -40*sum(diag LL)/B

#define BDIM 4096
#define HDIM 2048
#define BM 256
#define BN 256
#define HK 32                       // half-tile K depth
#define NH (HDIM / HK)              // 64 half-tiles
#define NBLK ((BDIM/BM) * (BDIM/BN))  // 256 blocks

typedef __attribute__((ext_vector_type(8))) short bf16x8;
typedef __attribute__((ext_vector_type(16))) float f32x16;

__device__ __forceinline__ unsigned short f2bf(float f) {
    unsigned int u = __float_as_uint(f);
    unsigned int r = (u + 0x7FFFu + ((u >> 16) & 1u)) >> 16;
    return (unsigned short)r;
}

__device__ __forceinline__ void gll16(const void* g, void* l) {
    __builtin_amdgcn_global_load_lds(
        (const __attribute__((address_space(1))) unsigned int*)g,
        (__attribute__((address_space(3))) unsigned int*)l,
        16, 0, 0);
}

// ---------------- Kernel 1: D-reduce + cast to bf16 ----------------
__global__ void reduce_cast(const float4* __restrict__ enc,
                            const float4* __restrict__ dec,
                            uint4* __restrict__ eb,
                            uint4* __restrict__ db) {
    int idx = blockIdx.x * blockDim.x + threadIdx.x;   // 0..1048575
    int b  = idx >> 8;
    int ch = idx & 255;
    int f4 = b * 1024 + ch * 2;

    {
        float4 a0 = enc[f4],       a1 = enc[f4 + 1];
        float4 c0 = enc[f4 + 512], c1 = enc[f4 + 512 + 1];
        uint4 o;
        o.x = (unsigned int)f2bf(a0.x + c0.x) | ((unsigned int)f2bf(a0.y + c0.y) << 16);
        o.y = (unsigned int)f2bf(a0.z + c0.z) | ((unsigned int)f2bf(a0.w + c0.w) << 16);
        o.z = (unsigned int)f2bf(a1.x + c1.x) | ((unsigned int)f2bf(a1.y + c1.y) << 16);
        o.w = (unsigned int)f2bf(a1.z + c1.z) | ((unsigned int)f2bf(a1.w + c1.w) << 16);
        eb[idx] = o;
    }
    {
        float4 a0 = dec[f4],       a1 = dec[f4 + 1];
        float4 c0 = dec[f4 + 512], c1 = dec[f4 + 512 + 1];
        uint4 o;
        o.x = (unsigned int)f2bf(a0.x + c0.x) | ((unsigned int)f2bf(a0.y + c0.y) << 16);
        o.y = (unsigned int)f2bf(a0.z + c0.z) | ((unsigned int)f2bf(a0.w + c0.w) << 16);
        o.z = (unsigned int)f2bf(a1.x + c1.x) | ((unsigned int)f2bf(a1.y + c1.y) << 16);
        o.w = (unsigned int)f2bf(a1.z + c1.z) | ((unsigned int)f2bf(a1.w + c1.w) << 16);
        db[idx] = o;
    }
}

// ---------------- Kernel 2: 32x32-MFMA pipelined 256x256 GEMM + fused log-sigmoid ----
// 8 waves (2M x 4N), per-wave 128x64 output: 4x2 fragments of 32x32, acc f32x16.
// LDS: ring of 4 slots, each A[256][32] + B[256][32] bf16 = 32 KiB -> 128 KiB.
// ONE phase per half-tile h (K=32): {12 ds_read_b128 + 4 global_load_lds ->
// barrier -> setprio + 16 MFMA_32x32x16 -> counted vmcnt -> barrier}.
// Slot rotation swizzle: LDS 16B-slot = (global_slot + (row>>1)) & 3.
__global__ __launch_bounds__(512, 2) void gemm_reduce(
        const unsigned short* __restrict__ eb,
        const unsigned short* __restrict__ db,
        float* __restrict__ pall,
        float* __restrict__ pdiag) {
    __shared__ __align__(16) unsigned short lds[4 * 16384];  // 128 KiB

    const int tid  = threadIdx.x;
    const int lane = tid & 63;
    const int wid  = tid >> 6;          // 0..7
    const int wr   = wid >> 2;          // 0..1  (M)
    const int wc   = wid & 3;           // 0..3  (N)
    const int bm   = blockIdx.y, bn = blockIdx.x;
    const int row0 = bm * BM, col0 = bn * BN;

    const int lo = lane & 31;           // fragment row (A) / col (B)
    const int hi = lane >> 5;           // k-half selector

    // staging: thread t writes LDS linear (row = t>>2, slot = t&3) within an 8KB chunk;
    // inverse-rotated global source col so read-side rotation sees linear k.
    const int su = tid >> 2;                         // row in 128-row chunk
    const int sg = ((tid & 3) - (su >> 1)) & 3;      // global 16B slot this thread fetches

    f32x16 acc[4][2] = {};

#define STAGE_A(s, kt) {                                                        \
    gll16(eb + (size_t)(row0 + su) * HDIM + (kt) + sg * 8,                      \
          &lds[(s) * 16384 + tid * 8]);                                         \
    gll16(eb + (size_t)(row0 + 128 + su) * HDIM + (kt) + sg * 8,                \
          &lds[(s) * 16384 + 4096 + tid * 8]); }
#define STAGE_B(s, kt) {                                                        \
    gll16(db + (size_t)(col0 + su) * HDIM + (kt) + sg * 8,                      \
          &lds[(s) * 16384 + 8192 + tid * 8]);                                  \
    gll16(db + (size_t)(col0 + 128 + su) * HDIM + (kt) + sg * 8,                \
          &lds[(s) * 16384 + 8192 + 4096 + tid * 8]); }

    // swizzled fragment read: LDS-half base, row r, k-slice ks (16 elem), k-half hi
#define LDF(base, r, ks) \
    (*(const bf16x8*)&(base)[(r) * 32 + (((((ks) * 2 + hi) + ((r) >> 1)) & 3) * 8)])

    // prologue: slots 0,1,2 (12 loads in flight)
    STAGE_A(0, 0)  STAGE_B(0, 0)
    STAGE_A(1, HK) STAGE_B(1, HK)
    STAGE_A(2, 2 * HK) STAGE_B(2, 2 * HK)
    asm volatile("s_waitcnt vmcnt(8)" ::: "memory");   // slot 0 landed
    __builtin_amdgcn_s_barrier();

#pragma unroll 4
    for (int h = 0; h < NH; ++h) {
        const unsigned short* SA = &lds[(h & 3) * 16384];
        const unsigned short* SB = SA + 8192;
        bf16x8 fa[4][2], fb[2][2];

        // 12 ds_read_b128 (A: 4 m-frags x 2 k-slices, B: 2 n-frags x 2)
#pragma unroll
        for (int m = 0; m < 4; ++m)
#pragma unroll
            for (int ks = 0; ks < 2; ++ks)
                fa[m][ks] = LDF(SA, wr * 128 + m * 32 + lo, ks);
#pragma unroll
        for (int n = 0; n < 2; ++n)
#pragma unroll
            for (int ks = 0; ks < 2; ++ks)
                fb[n][ks] = LDF(SB, wc * 64 + n * 32 + lo, ks);

        // prefetch slot h+3 (4 global_load_lds)
        if (h + 3 < NH) { STAGE_A((h + 3) & 3, (h + 3) * HK) STAGE_B((h + 3) & 3, (h + 3) * HK) }

        __builtin_amdgcn_s_barrier();
        __builtin_amdgcn_s_setprio(1);
#pragma unroll
        for (int ks = 0; ks < 2; ++ks)
#pragma unroll
            for (int m = 0; m < 4; ++m)
#pragma unroll
                for (int n = 0; n < 2; ++n)
                    acc[m][n] = __builtin_amdgcn_mfma_f32_32x32x16_bf16(
                        fa[m][ks], fb[n][ks], acc[m][n], 0, 0, 0);
        __builtin_amdgcn_s_setprio(0);

        // counted drain: slot h+1 must be landed before next iteration reads it
        if (h < NH - 3)       { asm volatile("s_waitcnt vmcnt(8)" ::: "memory"); }
        else if (h == NH - 3) { asm volatile("s_waitcnt vmcnt(4)" ::: "memory"); }
        else if (h == NH - 2) { asm volatile("s_waitcnt vmcnt(0)" ::: "memory"); }
        __builtin_amdgcn_s_barrier();
    }
#undef STAGE_A
#undef STAGE_B
#undef LDF

    // ---- epilogue: log-sigmoid + reduce ----
    // C/D layout (m74/m101): col = lane&31, row = (reg&3) + 8*(reg>>2) + 4*(lane>>5)
    const int rbase = row0 + wr * 128 + 4 * hi;
    const int cbase = col0 + wc * 64 + lo;
    float s_all = 0.f, s_diag = 0.f;
#pragma unroll
    for (int m = 0; m < 4; ++m) {
#pragma unroll
        for (int n = 0; n < 2; ++n) {
#pragma unroll
            for (int r = 0; r < 16; ++r) {
                float Sv = acc[m][n][r];
                int row = rbase + m * 32 + (r & 3) + 8 * (r >> 2);
                int col = cbase + n * 32;
                bool dg = (row == col);
                float x = dg ? Sv : -Sv;
                float ll = fminf(x, 0.f) - __logf(1.f + __expf(-fabsf(x)));
                s_all += ll;
                if (dg) s_diag += ll;
            }
        }
    }

#pragma unroll
    for (int off = 32; off; off >>= 1) {
        s_all  += __shfl_down(s_all, off);
        s_diag += __shfl_down(s_diag, off);
    }
    __syncthreads();                    // resync before LDS reuse
    float* red = (float*)lds;
    if (lane == 0) { red[wid] = s_all; red[8 + wid] = s_diag; }
    __syncthreads();
    if (tid == 0) {
        float A = 0.f, D = 0.f;
#pragma unroll
        for (int w = 0; w < 8; ++w) { A += red[w]; D += red[8 + w]; }
        int bflat = bm * gridDim.x + bn;
        pall[bflat]  = A;
        pdiag[bflat] = D;
    }
}

// ---------------- Kernel 3: finalize ----------------
__global__ void finalize(const float* __restrict__ pall,
                         const float* __restrict__ pdiag,
                         float* __restrict__ out) {
    float a = 0.f, d = 0.f;
    for (int i = threadIdx.x; i < NBLK; i += 256) { a += pall[i]; d += pdiag[i]; }
#pragma unroll
    for (int off = 32; off; off >>= 1) {
        a += __shfl_down(a, off);
        d += __shfl_down(d, off);
    }
    __shared__ float r[8];
    int wid = threadIdx.x >> 6, lane = threadIdx.x & 63;
    if (lane == 0) { r[wid] = a; r[4 + wid] = d; }
    __syncthreads();
    if (threadIdx.x == 0) {
        float A = r[0] + r[1] + r[2] + r[3];
        float D = r[4] + r[5] + r[6] + r[7];
        out[0] = -(A + 39.f * D) / (float)BDIM;  // logLoss
        out[1] = -(40.f * D) / (float)BDIM;      // diagonalLoss
    }
}

extern "C" void kernel_launch(void* const* d_in, const int* in_sizes, int n_in,
                              void* d_out, int out_size, void* d_ws, size_t ws_size,
                              hipStream_t stream) {
    const float* enc = (const float*)d_in[0];
    const float* dec = (const float*)d_in[1];
    float* out = (float*)d_out;

    char* ws = (char*)d_ws;
    unsigned short* eb = (unsigned short*)ws;
    unsigned short* db = (unsigned short*)(ws + (size_t)16 * 1024 * 1024);
    float* pall  = (float*)(ws + (size_t)32 * 1024 * 1024);
    float* pdiag = pall + NBLK;

    reduce_cast<<<4096, 256, 0, stream>>>(
        (const float4*)enc, (const float4*)dec, (uint4*)eb, (uint4*)db);

    dim3 grid(BDIM / BN, BDIM / BM);  // (16, 16) = 256 blocks = 1/CU
    gemm_reduce<<<grid, 512, 0, stream>>>(eb, db, pall, pdiag);

    finalize<<<1, 256, 0, stream>>>(pall, pdiag, out);
}

// Round 6
// 94.684 us; speedup vs baseline: 1.0869x; 1.0869x over previous
//
#include <hip/hip_runtime.h>

// Problem: B=4096, D=2, H=2048.
// e = sum_d enc[b,d,h]; d = sum_d dec[b,d,h]; S = e @ d^T (4096x4096)
// M = S on diag, -S off diag; LL = log_sigmoid(M)
// logLoss = -(sum(LL) + 39*sum(diag LL))/B ; diagonalLoss = -40*sum(diag LL)/B

#define BDIM 4096
#define HDIM 2048
#define BM 256
#define BN 256
#define HK 32                       // half-tile K depth
#define NH (HDIM / HK)              // 64 half-tiles
#define NBLK ((BDIM/BM) * (BDIM/BN))  // 256 blocks

typedef __attribute__((ext_vector_type(8))) short bf16x8;
typedef __attribute__((ext_vector_type(4))) float f32x4;

__device__ __forceinline__ unsigned short f2bf(float f) {
    unsigned int u = __float_as_uint(f);
    unsigned int r = (u + 0x7FFFu + ((u >> 16) & 1u)) >> 16;
    return (unsigned short)r;
}

__device__ __forceinline__ void gll16(const void* g, void* l) {
    __builtin_amdgcn_global_load_lds(
        (const __attribute__((address_space(1))) unsigned int*)g,
        (__attribute__((address_space(3))) unsigned int*)l,
        16, 0, 0);
}

// ---------------- Kernel 1: D-reduce + cast to bf16 ----------------
__global__ void reduce_cast(const float4* __restrict__ enc,
                            const float4* __restrict__ dec,
                            uint4* __restrict__ eb,
                            uint4* __restrict__ db) {
    int idx = blockIdx.x * blockDim.x + threadIdx.x;   // 0..1048575
    int b  = idx >> 8;
    int ch = idx & 255;
    int f4 = b * 1024 + ch * 2;

    {
        float4 a0 = enc[f4],       a1 = enc[f4 + 1];
        float4 c0 = enc[f4 + 512], c1 = enc[f4 + 512 + 1];
        uint4 o;
        o.x = (unsigned int)f2bf(a0.x + c0.x) | ((unsigned int)f2bf(a0.y + c0.y) << 16);
        o.y = (unsigned int)f2bf(a0.z + c0.z) | ((unsigned int)f2bf(a0.w + c0.w) << 16);
        o.z = (unsigned int)f2bf(a1.x + c1.x) | ((unsigned int)f2bf(a1.y + c1.y) << 16);
        o.w = (unsigned int)f2bf(a1.z + c1.z) | ((unsigned int)f2bf(a1.w + c1.w) << 16);
        eb[idx] = o;
    }
    {
        float4 a0 = dec[f4],       a1 = dec[f4 + 1];
        float4 c0 = dec[f4 + 512], c1 = dec[f4 + 512 + 1];
        uint4 o;
        o.x = (unsigned int)f2bf(a0.x + c0.x) | ((unsigned int)f2bf(a0.y + c0.y) << 16);
        o.y = (unsigned int)f2bf(a0.z + c0.z) | ((unsigned int)f2bf(a0.w + c0.w) << 16);
        o.z = (unsigned int)f2bf(a1.x + c1.x) | ((unsigned int)f2bf(a1.y + c1.y) << 16);
        o.w = (unsigned int)f2bf(a1.z + c1.z) | ((unsigned int)f2bf(a1.w + c1.w) << 16);
        db[idx] = o;
    }
}

// ---------------- Kernel 2: register-pipelined 256x256 GEMM + fused log-sigmoid ----
// 8 waves (2M x 4N), per-wave 128x64 output, acc[8][4] f32x4 (16x16x32 MFMA).
// LDS: ring of 4 slots, each A[256][32] + B[256][32] bf16 = 32 KiB -> 128 KiB.
// Register double-buffer: while MFMAs of half-tile h run on frag set X, the 12
// ds_read_b128 for h+1 fill set Y (independent regs -> LDS pipe overlaps MFMA
// pipe). ONE barrier per half-tile. Counted vmcnt(4): slot h+2 landed at the
// barrier ending half-tile h; reads of slot h+1 always after that guarantee.
// Slot rotation swizzle (R4-verified conflict-free for this read pattern).
__global__ __launch_bounds__(512, 2) void gemm_reduce(
        const unsigned short* __restrict__ eb,
        const unsigned short* __restrict__ db,
        float* __restrict__ pall,
        float* __restrict__ pdiag) {
    __shared__ __align__(16) unsigned short lds[4 * 16384];  // 128 KiB

    const int tid  = threadIdx.x;
    const int lane = tid & 63;
    const int wid  = tid >> 6;          // 0..7
    const int wr   = wid >> 2;          // 0..1  (M)
    const int wc   = wid & 3;           // 0..3  (N)
    const int bm   = blockIdx.y, bn = blockIdx.x;
    const int row0 = bm * BM, col0 = bn * BN;

    const int fr = lane & 15;                        // fragment row
    const int sl = ((lane >> 4) + (fr >> 1)) & 3;    // swizzled 16B slot (read side)

    // staging: thread t writes LDS linear (row = t>>2, slot = t&3) within an 8KB chunk;
    // inverse-rotated global source col so read-side rotation sees linear k.
    const int su = tid >> 2;                         // row in 128-row chunk
    const int sg = ((tid & 3) - (su >> 1)) & 3;      // global 16B slot this thread fetches

    f32x4 acc[8][4] = {};

#define STAGE_A(s, kt) {                                                        \
    gll16(eb + (size_t)(row0 + su) * HDIM + (kt) + sg * 8,                      \
          &lds[(s) * 16384 + tid * 8]);                                         \
    gll16(eb + (size_t)(row0 + 128 + su) * HDIM + (kt) + sg * 8,                \
          &lds[(s) * 16384 + 4096 + tid * 8]); }
#define STAGE_B(s, kt) {                                                        \
    gll16(db + (size_t)(col0 + su) * HDIM + (kt) + sg * 8,                      \
          &lds[(s) * 16384 + 8192 + tid * 8]);                                  \
    gll16(db + (size_t)(col0 + 128 + su) * HDIM + (kt) + sg * 8,                \
          &lds[(s) * 16384 + 8192 + 4096 + tid * 8]); }

    // read the full 12-fragment set for one half-tile from LDS slot base S_
#define READ_FRAG(FA, FB, S_) {                                                 \
    const unsigned short* S = (S_);                                             \
    _Pragma("unroll")                                                           \
    for (int m = 0; m < 8; ++m)                                                 \
        FA[m] = *(const bf16x8*)&S[(wr * 128 + m * 16 + fr) * 32 + sl * 8];     \
    _Pragma("unroll")                                                           \
    for (int n = 0; n < 4; ++n)                                                 \
        FB[n] = *(const bf16x8*)&S[8192 + (wc * 64 + n * 16 + fr) * 32 + sl * 8]; }

#define MFMA32(FA, FB) {                                                        \
    __builtin_amdgcn_s_setprio(1);                                              \
    _Pragma("unroll")                                                           \
    for (int m = 0; m < 8; ++m)                                                 \
        _Pragma("unroll")                                                       \
        for (int n = 0; n < 4; ++n)                                             \
            acc[m][n] = __builtin_amdgcn_mfma_f32_16x16x32_bf16(                \
                FA[m], FB[n], acc[m][n], 0, 0, 0);                              \
    __builtin_amdgcn_s_setprio(0); }

#define BARRIER() { __builtin_amdgcn_s_barrier(); asm volatile("" ::: "memory"); }

    // prologue: slots 0,1,2 (12 loads); slots 0,1 landed before first reads
    STAGE_A(0, 0)  STAGE_B(0, 0)
    STAGE_A(1, HK) STAGE_B(1, HK)
    STAGE_A(2, 2 * HK) STAGE_B(2, 2 * HK)
    asm volatile("s_waitcnt vmcnt(4)" ::: "memory");   // slots 0,1 landed (mine)
    BARRIER();                                          // ... and everyone's

    bf16x8 aE[8], bE[4], aO[8], bO[4];
    READ_FRAG(aE, bE, &lds[0]);                         // h=0 fragments

    for (int hh = 0; hh < NH; hh += 2) {
        // ---- half-tile hh: compute E, read O(h+1), stage h+3 ----
        if (hh + 1 < NH) READ_FRAG(aO, bO, &lds[((hh + 1) & 3) * 16384]);
        if (hh + 3 < NH) { STAGE_A((hh + 3) & 3, (hh + 3) * HK) STAGE_B((hh + 3) & 3, (hh + 3) * HK) }
        MFMA32(aE, bE);
        if (hh + 3 < NH)      { asm volatile("s_waitcnt vmcnt(4)" ::: "memory"); }
        else if (hh + 2 < NH) { asm volatile("s_waitcnt vmcnt(0)" ::: "memory"); }
        BARRIER();                                      // slot hh+2 landed (all waves)

        // ---- half-tile hh+1: compute O, read E(h+2), stage h+4 ----
        if (hh + 2 < NH) READ_FRAG(aE, bE, &lds[((hh + 2) & 3) * 16384]);
        if (hh + 4 < NH) { STAGE_A((hh + 4) & 3, (hh + 4) * HK) STAGE_B((hh + 4) & 3, (hh + 4) * HK) }
        MFMA32(aO, bO);
        if (hh + 4 < NH)      { asm volatile("s_waitcnt vmcnt(4)" ::: "memory"); }
        else if (hh + 3 < NH) { asm volatile("s_waitcnt vmcnt(0)" ::: "memory"); }
        BARRIER();                                      // slot hh+3 landed (all waves)
    }
#undef STAGE_A
#undef STAGE_B
#undef READ_FRAG
#undef MFMA32
#undef BARRIER

    // ---- epilogue: log-sigmoid + reduce ----
    // C/D layout: col = lane&15, row = (lane>>4)*4 + reg  (m89-verified)
    const int rbase = row0 + wr * 128 + ((lane >> 4) * 4);
    const int cbase = col0 + wc * 64 + fr;
    float s_all = 0.f, s_diag = 0.f;
#pragma unroll
    for (int m = 0; m < 8; ++m) {
#pragma unroll
        for (int n = 0; n < 4; ++n) {
#pragma unroll
            for (int r = 0; r < 4; ++r) {
                float Sv = acc[m][n][r];
                int row = rbase + m * 16 + r;
                int col = cbase + n * 16;
                bool dg = (row == col);
                float x = dg ? Sv : -Sv;
                float ll = fminf(x, 0.f) - __logf(1.f + __expf(-fabsf(x)));
                s_all += ll;
                if (dg) s_diag += ll;
            }
        }
    }

#pragma unroll
    for (int off = 32; off; off >>= 1) {
        s_all  += __shfl_down(s_all, off);
        s_diag += __shfl_down(s_diag, off);
    }
    __syncthreads();                    // resync before LDS reuse
    float* red = (float*)lds;
    if (lane == 0) { red[wid] = s_all; red[8 + wid] = s_diag; }
    __syncthreads();
    if (tid == 0) {
        float A = 0.f, D = 0.f;
#pragma unroll
        for (int w = 0; w < 8; ++w) { A += red[w]; D += red[8 + w]; }
        int bflat = bm * gridDim.x + bn;
        pall[bflat]  = A;
        pdiag[bflat] = D;
    }
}

// ---------------- Kernel 3: finalize ----------------
__global__ void finalize(const float* __restrict__ pall,
                         const float* __restrict__ pdiag,
                         float* __restrict__ out) {
    float a = 0.f, d = 0.f;
    for (int i = threadIdx.x; i < NBLK; i += 256) { a += pall[i]; d += pdiag[i]; }
#pragma unroll
    for (int off = 32; off; off >>= 1) {
        a += __shfl_down(a, off);
        d += __shfl_down(d, off);
    }
    __shared__ float r[8];
    int wid = threadIdx.x >> 6, lane = threadIdx.x & 63;
    if (lane == 0) { r[wid] = a; r[4 + wid] = d; }
    __syncthreads();
    if (threadIdx.x == 0) {
        float A = r[0] + r[1] + r[2] + r[3];
        float D = r[4] + r[5] + r[6] + r[7];
        out[0] = -(A + 39.f * D) / (float)BDIM;  // logLoss
        out[1] = -(40.f * D) / (float)BDIM;      // diagonalLoss
    }
}

extern "C" void kernel_launch(void* const* d_in, const int* in_sizes, int n_in,
                              void* d_out, int out_size, void* d_ws, size_t ws_size,
                              hipStream_t stream) {
    const float* enc = (const float*)d_in[0];
    const float* dec = (const float*)d_in[1];
    float* out = (float*)d_out;

    char* ws = (char*)d_ws;
    unsigned short* eb = (unsigned short*)ws;
    unsigned short* db = (unsigned short*)(ws + (size_t)16 * 1024 * 1024);
    float* pall  = (float*)(ws + (size_t)32 * 1024 * 1024);
    float* pdiag = pall + NBLK;

    reduce_cast<<<4096, 256, 0, stream>>>(
        (const float4*)enc, (const float4*)dec, (uint4*)eb, (uint4*)db);

    dim3 grid(BDIM / BN, BDIM / BM);  // (16, 16) = 256 blocks = 1/CU
    gemm_reduce<<<grid, 512, 0, stream>>>(eb, db, pall, pdiag);

    finalize<<<1, 256, 0, stream>>>(pall, pdiag, out);
}

// Round 7
// 91.014 us; speedup vs baseline: 1.1307x; 1.0403x over previous
//
#include <hip/hip_runtime.h>

// Problem: B=4096, D=2, H=2048.
// e = sum_d enc[b,d,h]; d = sum_d dec[b,d,h]; S = e @ d^T (4096x4096)
// M = S on diag, -S off diag; LL = log_sigmoid(M)
// logLoss = -(sum(LL) + 39*sum(diag LL))/B ; diagonalLoss = -40*sum(diag LL)/B

#define BDIM 4096
#define HDIM 2048
#define BM 256
#define BN 256
#define BK 64
#define NT (HDIM / BK)               // 32 K-tiles
#define NBLK ((BDIM/BM) * (BDIM/BN)) // 256 blocks

typedef __attribute__((ext_vector_type(8))) short bf16x8;
typedef __attribute__((ext_vector_type(4))) float f32x4;

__device__ __forceinline__ unsigned short f2bf(float f) {
    unsigned int u = __float_as_uint(f);
    unsigned int r = (u + 0x7FFFu + ((u >> 16) & 1u)) >> 16;
    return (unsigned short)r;
}

__device__ __forceinline__ void gll16(const void* g, void* l) {
    __builtin_amdgcn_global_load_lds(
        (const __attribute__((address_space(1))) unsigned int*)g,
        (__attribute__((address_space(3))) unsigned int*)l,
        16, 0, 0);
}

// ---------------- Kernel 1: D-reduce + cast to bf16 ----------------
__global__ void reduce_cast(const float4* __restrict__ enc,
                            const float4* __restrict__ dec,
                            uint4* __restrict__ eb,
                            uint4* __restrict__ db) {
    int idx = blockIdx.x * blockDim.x + threadIdx.x;   // 0..1048575
    int b  = idx >> 8;
    int ch = idx & 255;
    int f4 = b * 1024 + ch * 2;

    {
        float4 a0 = enc[f4],       a1 = enc[f4 + 1];
        float4 c0 = enc[f4 + 512], c1 = enc[f4 + 512 + 1];
        uint4 o;
        o.x = (unsigned int)f2bf(a0.x + c0.x) | ((unsigned int)f2bf(a0.y + c0.y) << 16);
        o.y = (unsigned int)f2bf(a0.z + c0.z) | ((unsigned int)f2bf(a0.w + c0.w) << 16);
        o.z = (unsigned int)f2bf(a1.x + c1.x) | ((unsigned int)f2bf(a1.y + c1.y) << 16);
        o.w = (unsigned int)f2bf(a1.z + c1.z) | ((unsigned int)f2bf(a1.w + c1.w) << 16);
        eb[idx] = o;
    }
    {
        float4 a0 = dec[f4],       a1 = dec[f4 + 1];
        float4 c0 = dec[f4 + 512], c1 = dec[f4 + 512 + 1];
        uint4 o;
        o.x = (unsigned int)f2bf(a0.x + c0.x) | ((unsigned int)f2bf(a0.y + c0.y) << 16);
        o.y = (unsigned int)f2bf(a0.z + c0.z) | ((unsigned int)f2bf(a0.w + c0.w) << 16);
        o.z = (unsigned int)f2bf(a1.x + c1.x) | ((unsigned int)f2bf(a1.y + c1.y) << 16);
        o.w = (unsigned int)f2bf(a1.z + c1.z) | ((unsigned int)f2bf(a1.w + c1.w) << 16);
        db[idx] = o;
    }
}

// ------------- Kernel 2: m201-style 4-phase/K-tile 256x256 GEMM + fused log-sigmoid -------------
// 8 waves (2M x 4N), per-wave 128x64 output, acc[8][4] f32x4 (16x16x32 MFMA), BK=64.
// LDS 128 KiB: A[2dbuf][256][64] + B[2dbuf][256][64] bf16. Half-tile staging (2 gll each).
// Per K-tile tau, 4 phases, each {ds-subtile reads ; 1 half-tile stage ; BAR ; lgkmcnt(0) ;
// setprio(1) 16 MFMA setprio(0) ; BAR}; single counted vmcnt(4) gate at P4 (never 0 in steady).
// Stage schedule: P1: A-lo(tau+1), P2: A-hi(tau+1), P3: B-lo(tau+2), P4: B-hi(tau+2).
// Ledger: entering tau outstanding = B(tau+1)=4 loads; +8 in tau; vmcnt(4) => tile tau+1 landed.
// Swizzle: LDS 16B-slot = global_slot ^ (row&7), applied on read; source col inverse-XOR'd,
// gll dest linear (both-sides rule). b128 bank math: 8 accesses/bank = free minimum.
__global__ __launch_bounds__(512, 2) void gemm_reduce(
        const unsigned short* __restrict__ eb,
        const unsigned short* __restrict__ db,
        float* __restrict__ pall,
        float* __restrict__ pdiag) {
    __shared__ __align__(16) unsigned short lds[65536];  // 128 KiB: A 0..32767, B 32768..65535

    const int tid  = threadIdx.x;
    const int lane = tid & 63;
    const int wid  = tid >> 6;          // 0..7
    const int wr   = wid >> 2;          // 0..1  (M)
    const int wc   = wid & 3;           // 0..3  (N)
    const int bm   = blockIdx.y, bn = blockIdx.x;
    const int row0 = bm * BM, col0 = bn * BN;

    const int fr = lane & 15;           // fragment row
    const int kq = lane >> 4;           // k-quarter (8-elem group within 32)

    // staging: thread t covers (row = j*64 + t>>3, lds 16B-slot = t&7) of a 128x64 half-tile;
    // global col slot inverse-XOR'd so LDS linear dest + XOR read = identity.
    const int su = tid >> 3;                              // 0..63
    const int sx = (((tid & 7) ^ (su & 7)) << 3);         // global col elem offset

    f32x4 acc[8][4] = {};

    // ---- stage macros: half-tile (128 rows x 64 cols) = 2 gll16 ----
#define ST_ALO(tp) { const int kt = (tp) * BK; unsigned short* d = &lds[((tp) & 1) * 16384]; \
    gll16(eb + (size_t)(row0 + su)      * HDIM + kt + sx, d + tid * 8);                      \
    gll16(eb + (size_t)(row0 + 64 + su) * HDIM + kt + sx, d + 4096 + tid * 8); }
#define ST_AHI(tp) { const int kt = (tp) * BK; unsigned short* d = &lds[((tp) & 1) * 16384 + 8192]; \
    gll16(eb + (size_t)(row0 + 128 + su) * HDIM + kt + sx, d + tid * 8);                     \
    gll16(eb + (size_t)(row0 + 192 + su) * HDIM + kt + sx, d + 4096 + tid * 8); }
#define ST_BLO(tp) { const int kt = (tp) * BK; unsigned short* d = &lds[32768 + ((tp) & 1) * 16384]; \
    gll16(db + (size_t)(col0 + su)      * HDIM + kt + sx, d + tid * 8);                      \
    gll16(db + (size_t)(col0 + 64 + su) * HDIM + kt + sx, d + 4096 + tid * 8); }
#define ST_BHI(tp) { const int kt = (tp) * BK; unsigned short* d = &lds[32768 + ((tp) & 1) * 16384 + 8192]; \
    gll16(db + (size_t)(col0 + 128 + su) * HDIM + kt + sx, d + tid * 8);                     \
    gll16(db + (size_t)(col0 + 192 + su) * HDIM + kt + sx, d + 4096 + tid * 8); }

    // ---- swizzled fragment reads (row&7 == fr&7 since bases are mult of 16) ----
#define RD_A(buf, mi, ks) \
    (*(const bf16x8*)&lds[(buf) * 16384 + (wr * 128 + (mi) * 16 + fr) * 64 + \
                          ((((ks) * 4 + kq) ^ (fr & 7)) << 3)])
#define RD_B(buf, ni, ks) \
    (*(const bf16x8*)&lds[32768 + (buf) * 16384 + (wc * 64 + (ni) * 16 + fr) * 64 + \
                          ((((ks) * 4 + kq) ^ (fr & 7)) << 3)])

#define BARM() { __builtin_amdgcn_s_barrier(); asm volatile("" ::: "memory"); }
#define LGKM0() asm volatile("s_waitcnt lgkmcnt(0)" ::: "memory")

#define MFMA8(AM, BM_, mo, no) {                                                 \
    __builtin_amdgcn_s_setprio(1);                                               \
    _Pragma("unroll")                                                            \
    for (int ks = 0; ks < 2; ++ks)                                               \
        _Pragma("unroll")                                                        \
        for (int m = 0; m < 4; ++m)                                              \
            _Pragma("unroll")                                                    \
            for (int n = 0; n < 2; ++n)                                          \
                acc[(mo) + m][(no) + n] = __builtin_amdgcn_mfma_f32_16x16x32_bf16( \
                    AM[m][ks], BM_[n][ks], acc[(mo) + m][(no) + n], 0, 0, 0);    \
    __builtin_amdgcn_s_setprio(0); }

    // one K-tile = 4 phases; buf is compile-time via unroll-by-2
#define TILE(tau, buf) {                                                         \
    bf16x8 aF[4][2], bL[2][2], bH[2][2];                                         \
    /* P1: a0-3, b0-1; stage A-lo(tau+1) */                                      \
    _Pragma("unroll") for (int m = 0; m < 4; ++m)                                \
        _Pragma("unroll") for (int ks = 0; ks < 2; ++ks)                         \
            aF[m][ks] = RD_A(buf, m, ks);                                        \
    _Pragma("unroll") for (int n = 0; n < 2; ++n)                                \
        _Pragma("unroll") for (int ks = 0; ks < 2; ++ks)                         \
            bL[n][ks] = RD_B(buf, n, ks);                                        \
    if ((tau) + 1 < NT) ST_ALO((tau) + 1)                                        \
    BARM(); LGKM0();                                                             \
    MFMA8(aF, bL, 0, 0);                                                         \
    BARM();                                                                      \
    /* P2: b2-3; stage A-hi(tau+1) */                                            \
    _Pragma("unroll") for (int n = 0; n < 2; ++n)                                \
        _Pragma("unroll") for (int ks = 0; ks < 2; ++ks)                         \
            bH[n][ks] = RD_B(buf, 2 + n, ks);                                    \
    if ((tau) + 1 < NT) ST_AHI((tau) + 1)                                        \
    BARM(); LGKM0();                                                             \
    MFMA8(aF, bH, 0, 2);                                                         \
    BARM();                                                                      \
    /* P3: a4-7; stage B-lo(tau+2) */                                            \
    _Pragma("unroll") for (int m = 0; m < 4; ++m)                                \
        _Pragma("unroll") for (int ks = 0; ks < 2; ++ks)                         \
            aF[m][ks] = RD_A(buf, 4 + m, ks);                                    \
    if ((tau) + 2 < NT) ST_BLO((tau) + 2)                                        \
    BARM(); LGKM0();                                                             \
    MFMA8(aF, bH, 4, 2);                                                         \
    BARM();                                                                      \
    /* P4: no reads; stage B-hi(tau+2); gate */                                  \
    if ((tau) + 2 < NT) ST_BHI((tau) + 2)                                        \
    BARM();                                                                      \
    MFMA8(aF, bL, 4, 0);                                                         \
    if ((tau) < NT - 2)       { asm volatile("s_waitcnt vmcnt(4)" ::: "memory"); } \
    else if ((tau) == NT - 2) { asm volatile("s_waitcnt vmcnt(0)" ::: "memory"); } \
    BARM(); }

    // prologue: tile 0 (4 half-tiles) + B(1) (as-if P3/P4 of tile -1)
    ST_ALO(0) ST_AHI(0) ST_BLO(0) ST_BHI(0)
    ST_BLO(1) ST_BHI(1)
    asm volatile("s_waitcnt vmcnt(4)" ::: "memory");   // tile 0 landed; B(1) in flight
    BARM();

    for (int tt = 0; tt < NT; tt += 2) {
        TILE(tt, 0)
        TILE(tt + 1, 1)
    }
#undef TILE
#undef MFMA8
#undef RD_A
#undef RD_B
#undef ST_ALO
#undef ST_AHI
#undef ST_BLO
#undef ST_BHI
#undef BARM
#undef LGKM0

    // ---- epilogue: log-sigmoid + reduce ----
    // C/D layout: col = lane&15, row = (lane>>4)*4 + reg  (m89-verified)
    const int rbase = row0 + wr * 128 + (kq * 4);
    const int cbase = col0 + wc * 64 + fr;
    float s_all = 0.f, s_diag = 0.f;
#pragma unroll
    for (int m = 0; m < 8; ++m) {
#pragma unroll
        for (int n = 0; n < 4; ++n) {
#pragma unroll
            for (int r = 0; r < 4; ++r) {
                float Sv = acc[m][n][r];
                int row = rbase + m * 16 + r;
                int col = cbase + n * 16;
                bool dg = (row == col);
                float x = dg ? Sv : -Sv;
                float ll = fminf(x, 0.f) - __logf(1.f + __expf(-fabsf(x)));
                s_all += ll;
                if (dg) s_diag += ll;
            }
        }
    }

#pragma unroll
    for (int off = 32; off; off >>= 1) {
        s_all  += __shfl_down(s_all, off);
        s_diag += __shfl_down(s_diag, off);
    }
    __syncthreads();                    // resync before LDS reuse
    float* red = (float*)lds;
    if (lane == 0) { red[wid] = s_all; red[8 + wid] = s_diag; }
    __syncthreads();
    if (tid == 0) {
        float A = 0.f, D = 0.f;
#pragma unroll
        for (int w = 0; w < 8; ++w) { A += red[w]; D += red[8 + w]; }
        int bflat = bm * gridDim.x + bn;
        pall[bflat]  = A;
        pdiag[bflat] = D;
    }
}

// ---------------- Kernel 3: finalize ----------------
__global__ void finalize(const float* __restrict__ pall,
                         const float* __restrict__ pdiag,
                         float* __restrict__ out) {
    float a = 0.f, d = 0.f;
    for (int i = threadIdx.x; i < NBLK; i += 256) { a += pall[i]; d += pdiag[i]; }
#pragma unroll
    for (int off = 32; off; off >>= 1) {
        a += __shfl_down(a, off);
        d += __shfl_down(d, off);
    }
    __shared__ float r[8];
    int wid = threadIdx.x >> 6, lane = threadIdx.x & 63;
    if (lane == 0) { r[wid] = a; r[4 + wid] = d; }
    __syncthreads();
    if (threadIdx.x == 0) {
        float A = r[0] + r[1] + r[2] + r[3];
        float D = r[4] + r[5] + r[6] + r[7];
        out[0] = -(A + 39.f * D) / (float)BDIM;  // logLoss
        out[1] = -(40.f * D) / (float)BDIM;      // diagonalLoss
    }
}

extern "C" void kernel_launch(void* const* d_in, const int* in_sizes, int n_in,
                              void* d_out, int out_size, void* d_ws, size_t ws_size,
                              hipStream_t stream) {
    const float* enc = (const float*)d_in[0];
    const float* dec = (const float*)d_in[1];
    float* out = (float*)d_out;

    char* ws = (char*)d_ws;
    unsigned short* eb = (unsigned short*)ws;
    unsigned short* db = (unsigned short*)(ws + (size_t)16 * 1024 * 1024);
    float* pall  = (float*)(ws + (size_t)32 * 1024 * 1024);
    float* pdiag = pall + NBLK;

    reduce_cast<<<4096, 256, 0, stream>>>(
        (const float4*)enc, (const float4*)dec, (uint4*)eb, (uint4*)db);

    dim3 grid(BDIM / BN, BDIM / BM);  // (16, 16) = 256 blocks = 1/CU
    gemm_reduce<<<grid, 512, 0, stream>>>(eb, db, pall, pdiag);

    finalize<<<1, 256, 0, stream>>>(pall, pdiag, out);
}

// Round 8
// 89.865 us; speedup vs baseline: 1.1452x; 1.0128x over previous
//
#include <hip/hip_runtime.h>

// Problem: B=4096, D=2, H=2048.
// e = sum_d enc[b,d,h]; d = sum_d dec[b,d,h]; S = e @ d^T (4096x4096)
// M = S on diag, -S off diag; LL = log_sigmoid(M)
// logLoss = -(sum(LL) + 39*sum(diag LL))/B ; diagonalLoss = -40*sum(diag LL)/B

#define BDIM 4096
#define HDIM 2048
#define BM 256
#define BN 256
#define BK 64
#define NT (HDIM / BK)               // 32 K-tiles
#define NBLK ((BDIM/BM) * (BDIM/BN)) // 256 blocks

typedef __attribute__((ext_vector_type(8))) short bf16x8;
typedef __attribute__((ext_vector_type(4))) float f32x4;

__device__ __forceinline__ unsigned short f2bf(float f) {
    unsigned int u = __float_as_uint(f);
    unsigned int r = (u + 0x7FFFu + ((u >> 16) & 1u)) >> 16;
    return (unsigned short)r;
}

__device__ __forceinline__ void gll16(const void* g, void* l) {
    __builtin_amdgcn_global_load_lds(
        (const __attribute__((address_space(1))) unsigned int*)g,
        (__attribute__((address_space(3))) unsigned int*)l,
        16, 0, 0);
}

// ---------------- Kernel 1: D-reduce + cast to bf16 ----------------
__global__ void reduce_cast(const float4* __restrict__ enc,
                            const float4* __restrict__ dec,
                            uint4* __restrict__ eb,
                            uint4* __restrict__ db) {
    int idx = blockIdx.x * blockDim.x + threadIdx.x;   // 0..1048575
    int b  = idx >> 8;
    int ch = idx & 255;
    int f4 = b * 1024 + ch * 2;

    {
        float4 a0 = enc[f4],       a1 = enc[f4 + 1];
        float4 c0 = enc[f4 + 512], c1 = enc[f4 + 512 + 1];
        uint4 o;
        o.x = (unsigned int)f2bf(a0.x + c0.x) | ((unsigned int)f2bf(a0.y + c0.y) << 16);
        o.y = (unsigned int)f2bf(a0.z + c0.z) | ((unsigned int)f2bf(a0.w + c0.w) << 16);
        o.z = (unsigned int)f2bf(a1.x + c1.x) | ((unsigned int)f2bf(a1.y + c1.y) << 16);
        o.w = (unsigned int)f2bf(a1.z + c1.z) | ((unsigned int)f2bf(a1.w + c1.w) << 16);
        eb[idx] = o;
    }
    {
        float4 a0 = dec[f4],       a1 = dec[f4 + 1];
        float4 c0 = dec[f4 + 512], c1 = dec[f4 + 512 + 1];
        uint4 o;
        o.x = (unsigned int)f2bf(a0.x + c0.x) | ((unsigned int)f2bf(a0.y + c0.y) << 16);
        o.y = (unsigned int)f2bf(a0.z + c0.z) | ((unsigned int)f2bf(a0.w + c0.w) << 16);
        o.z = (unsigned int)f2bf(a1.x + c1.x) | ((unsigned int)f2bf(a1.y + c1.y) << 16);
        o.w = (unsigned int)f2bf(a1.z + c1.z) | ((unsigned int)f2bf(a1.w + c1.w) << 16);
        db[idx] = o;
    }
}

// ------------- Kernel 2: fence-light 2-phase 256x256 GEMM + fused log-sigmoid -------------
// 8 waves (2M x 4N), per-wave 128x64 output, acc[8][4] f32x4 (16x16x32 MFMA), BK=64.
// LDS 128 KiB: A[2dbuf][256][64] + B[2dbuf][256][64] bf16.
// Per K-tile: {8 gll stage(tile+1 -> buf^1) ; 24 ds_read + 64 MFMA, UNFENCED (compiler
// interleaves via fine-grained lgkmcnt — m97 asm evidence) ; lgkmcnt(0)+vmcnt(0) ;
// bare s_barrier}. ONE barrier per tile. vmcnt(0) exposed latency ~0: glls issued
// ~2300 cyc before the gate >> HBM latency. No setprio / sched pins (they fence).
// Swizzle: LDS 16B-slot = global_slot ^ (row&7) on read; source col inverse-XOR'd,
// gll dest linear (both-sides rule). Verified 0-conflict in R7.
__global__ __launch_bounds__(512, 2) void gemm_reduce(
        const unsigned short* __restrict__ eb,
        const unsigned short* __restrict__ db,
        float* __restrict__ pall,
        float* __restrict__ pdiag) {
    __shared__ __align__(16) unsigned short lds[65536];  // 128 KiB: A 0..32767, B 32768..65535

    const int tid  = threadIdx.x;
    const int lane = tid & 63;
    const int wid  = tid >> 6;          // 0..7
    const int wr   = wid >> 2;          // 0..1  (M)
    const int wc   = wid & 3;           // 0..3  (N)
    const int bm   = blockIdx.y, bn = blockIdx.x;
    const int row0 = bm * BM, col0 = bn * BN;

    const int fr = lane & 15;           // fragment row
    const int kq = lane >> 4;           // k-quarter (8-elem group within 32)

    // staging: thread t covers (row = j*64 + t>>3, lds 16B-slot = t&7) of a 128x64 half-tile;
    // global col slot inverse-XOR'd so LDS linear dest + XOR read = identity.
    const int su = tid >> 3;                              // 0..63
    const int sx = (((tid & 7) ^ (su & 7)) << 3);         // global col elem offset

    f32x4 acc[8][4] = {};

    // ---- stage macros: half-tile (128 rows x 64 cols) = 2 gll16; buf = (tp)&1 ----
#define ST_ALO(tp) { const int kt = (tp) * BK; unsigned short* d = &lds[((tp) & 1) * 16384]; \
    gll16(eb + (size_t)(row0 + su)      * HDIM + kt + sx, d + tid * 8);                      \
    gll16(eb + (size_t)(row0 + 64 + su) * HDIM + kt + sx, d + 4096 + tid * 8); }
#define ST_AHI(tp) { const int kt = (tp) * BK; unsigned short* d = &lds[((tp) & 1) * 16384 + 8192]; \
    gll16(eb + (size_t)(row0 + 128 + su) * HDIM + kt + sx, d + tid * 8);                     \
    gll16(eb + (size_t)(row0 + 192 + su) * HDIM + kt + sx, d + 4096 + tid * 8); }
#define ST_BLO(tp) { const int kt = (tp) * BK; unsigned short* d = &lds[32768 + ((tp) & 1) * 16384]; \
    gll16(db + (size_t)(col0 + su)      * HDIM + kt + sx, d + tid * 8);                      \
    gll16(db + (size_t)(col0 + 64 + su) * HDIM + kt + sx, d + 4096 + tid * 8); }
#define ST_BHI(tp) { const int kt = (tp) * BK; unsigned short* d = &lds[32768 + ((tp) & 1) * 16384 + 8192]; \
    gll16(db + (size_t)(col0 + 128 + su) * HDIM + kt + sx, d + tid * 8);                     \
    gll16(db + (size_t)(col0 + 192 + su) * HDIM + kt + sx, d + 4096 + tid * 8); }

    // ---- swizzled fragment reads (row&7 == fr&7 since bases are mult of 16) ----
#define RD_A(buf, mi, ks) \
    (*(const bf16x8*)&lds[(buf) * 16384 + (wr * 128 + (mi) * 16 + fr) * 64 + \
                          ((((ks) * 4 + kq) ^ (fr & 7)) << 3)])
#define RD_B(buf, ni, ks) \
    (*(const bf16x8*)&lds[32768 + (buf) * 16384 + (wc * 64 + (ni) * 16 + fr) * 64 + \
                          ((((ks) * 4 + kq) ^ (fr & 7)) << 3)])

#define MFMA16(AM, BM_, mo, no) {                                                \
    _Pragma("unroll")                                                            \
    for (int ks = 0; ks < 2; ++ks)                                               \
        _Pragma("unroll")                                                        \
        for (int m = 0; m < 4; ++m)                                              \
            _Pragma("unroll")                                                    \
            for (int n = 0; n < 2; ++n)                                          \
                acc[(mo) + m][(no) + n] = __builtin_amdgcn_mfma_f32_16x16x32_bf16( \
                    AM[m][ks], BM_[n][ks], acc[(mo) + m][(no) + n], 0, 0, 0);    \
}

    // one K-tile: stage next, read all 24 frags, 64 MFMA, single gate+barrier
#define TILE(tau, buf) {                                                         \
    if ((tau) + 1 < NT) { ST_ALO((tau)+1) ST_AHI((tau)+1) ST_BLO((tau)+1) ST_BHI((tau)+1) } \
    bf16x8 aL[4][2], aH[4][2], b0[2][2], b1[2][2];                               \
    _Pragma("unroll") for (int m = 0; m < 4; ++m)                                \
        _Pragma("unroll") for (int ks = 0; ks < 2; ++ks)                         \
            aL[m][ks] = RD_A(buf, m, ks);                                        \
    _Pragma("unroll") for (int n = 0; n < 2; ++n)                                \
        _Pragma("unroll") for (int ks = 0; ks < 2; ++ks)                         \
            b0[n][ks] = RD_B(buf, n, ks);                                        \
    _Pragma("unroll") for (int n = 0; n < 2; ++n)                                \
        _Pragma("unroll") for (int ks = 0; ks < 2; ++ks)                         \
            b1[n][ks] = RD_B(buf, 2 + n, ks);                                    \
    _Pragma("unroll") for (int m = 0; m < 4; ++m)                                \
        _Pragma("unroll") for (int ks = 0; ks < 2; ++ks)                         \
            aH[m][ks] = RD_A(buf, 4 + m, ks);                                    \
    MFMA16(aL, b0, 0, 0);                                                        \
    MFMA16(aL, b1, 0, 2);                                                        \
    MFMA16(aH, b1, 4, 2);                                                        \
    MFMA16(aH, b0, 4, 0);                                                        \
    asm volatile("s_waitcnt lgkmcnt(0) vmcnt(0)" ::: "memory");                  \
    __builtin_amdgcn_s_barrier(); }

    // prologue: tile 0 -> buf0
    ST_ALO(0) ST_AHI(0) ST_BLO(0) ST_BHI(0)
    asm volatile("s_waitcnt vmcnt(0)" ::: "memory");
    __builtin_amdgcn_s_barrier();

    for (int tt = 0; tt < NT; tt += 2) {
        TILE(tt, 0)
        TILE(tt + 1, 1)
    }
#undef TILE
#undef MFMA16
#undef RD_A
#undef RD_B
#undef ST_ALO
#undef ST_AHI
#undef ST_BLO
#undef ST_BHI

    // ---- epilogue: log-sigmoid + reduce ----
    // C/D layout: col = lane&15, row = (lane>>4)*4 + reg  (m89-verified)
    const int rbase = row0 + wr * 128 + (kq * 4);
    const int cbase = col0 + wc * 64 + fr;
    float s_all = 0.f, s_diag = 0.f;
#pragma unroll
    for (int m = 0; m < 8; ++m) {
#pragma unroll
        for (int n = 0; n < 4; ++n) {
#pragma unroll
            for (int r = 0; r < 4; ++r) {
                float Sv = acc[m][n][r];
                int row = rbase + m * 16 + r;
                int col = cbase + n * 16;
                bool dg = (row == col);
                float x = dg ? Sv : -Sv;
                float ll = fminf(x, 0.f) - __logf(1.f + __expf(-fabsf(x)));
                s_all += ll;
                if (dg) s_diag += ll;
            }
        }
    }

#pragma unroll
    for (int off = 32; off; off >>= 1) {
        s_all  += __shfl_down(s_all, off);
        s_diag += __shfl_down(s_diag, off);
    }
    __syncthreads();                    // resync before LDS reuse
    float* red = (float*)lds;
    if (lane == 0) { red[wid] = s_all; red[8 + wid] = s_diag; }
    __syncthreads();
    if (tid == 0) {
        float A = 0.f, D = 0.f;
#pragma unroll
        for (int w = 0; w < 8; ++w) { A += red[w]; D += red[8 + w]; }
        int bflat = bm * gridDim.x + bn;
        pall[bflat]  = A;
        pdiag[bflat] = D;
    }
}

// ---------------- Kernel 3: finalize ----------------
__global__ void finalize(const float* __restrict__ pall,
                         const float* __restrict__ pdiag,
                         float* __restrict__ out) {
    float a = 0.f, d = 0.f;
    for (int i = threadIdx.x; i < NBLK; i += 256) { a += pall[i]; d += pdiag[i]; }
#pragma unroll
    for (int off = 32; off; off >>= 1) {
        a += __shfl_down(a, off);
        d += __shfl_down(d, off);
    }
    __shared__ float r[8];
    int wid = threadIdx.x >> 6, lane = threadIdx.x & 63;
    if (lane == 0) { r[wid] = a; r[4 + wid] = d; }
    __syncthreads();
    if (threadIdx.x == 0) {
        float A = r[0] + r[1] + r[2] + r[3];
        float D = r[4] + r[5] + r[6] + r[7];
        out[0] = -(A + 39.f * D) / (float)BDIM;  // logLoss
        out[1] = -(40.f * D) / (float)BDIM;      // diagonalLoss
    }
}

extern "C" void kernel_launch(void* const* d_in, const int* in_sizes, int n_in,
                              void* d_out, int out_size, void* d_ws, size_t ws_size,
                              hipStream_t stream) {
    const float* enc = (const float*)d_in[0];
    const float* dec = (const float*)d_in[1];
    float* out = (float*)d_out;

    char* ws = (char*)d_ws;
    unsigned short* eb = (unsigned short*)ws;
    unsigned short* db = (unsigned short*)(ws + (size_t)16 * 1024 * 1024);
    float* pall  = (float*)(ws + (size_t)32 * 1024 * 1024);
    float* pdiag = pall + NBLK;

    reduce_cast<<<4096, 256, 0, stream>>>(
        (const float4*)enc, (const float4*)dec, (uint4*)eb, (uint4*)db);

    dim3 grid(BDIM / BN, BDIM / BM);  // (16, 16) = 256 blocks = 1/CU
    gemm_reduce<<<grid, 512, 0, stream>>>(eb, db, pall, pdiag);

    finalize<<<1, 256, 0, stream>>>(pall, pdiag, out);
}